// Round 4
// baseline (385.211 us; speedup 1.0000x reference)
//
#include <hip/hip_runtime.h>
#include <math.h>
#include <cstddef>

#define BB 4
#define LL 4096
#define DD 256
#define NST 8
#define RANK 16
#define HID 128
#define BL (BB*LL)          // 16384
#define BLD ((size_t)BL*DD) // 4194304
#define CH 64               // scan chunks
#define CLEN 64             // steps per chunk (CH*CLEN == LL)

typedef __bf16 bf16x8 __attribute__((ext_vector_type(8)));
typedef float  f32x4  __attribute__((ext_vector_type(4)));

__device__ __forceinline__ float siluf(float x){ return x / (1.f + __expf(-x)); }
__device__ __forceinline__ float softplusf_(float x){
  return fmaxf(x, 0.f) + log1pf(__expf(-fabsf(x)));
}
// fp32 -> bf16 bits, round-to-nearest-even
__device__ __forceinline__ unsigned short f2bf(float x){
  union { float f; unsigned u; } v; v.f = x;
  unsigned r = v.u + 0x7fffu + ((v.u >> 16) & 1u);
  return (unsigned short)(r >> 16);
}
__device__ __forceinline__ float bf2f(unsigned short u){
  union { unsigned u32; float f; } c; c.u32 = ((unsigned)u) << 16;
  return c.f;
}

// ---------------- RMSNorm: h0 -> bf16, h1 -> fp32 --------------------------------
__global__ __launch_bounds__(64) void rms_kernel(
    const float* __restrict__ x0, const float* __restrict__ w0, unsigned short* __restrict__ o0b,
    const float* __restrict__ x1, const float* __restrict__ w1, float* __restrict__ o1)
{
  const float* x; const float* w;
  if (blockIdx.y == 0){ x = x0; w = w0; } else { x = x1; w = w1; }
  size_t tok = blockIdx.x;
  int lane = threadIdx.x;
  float4 v = ((const float4*)(x + tok*DD))[lane];
  float s = v.x*v.x + v.y*v.y + v.z*v.z + v.w*v.w;
  #pragma unroll
  for (int m = 1; m < 64; m <<= 1) s += __shfl_xor(s, m, 64);
  float scale = 1.f / (sqrtf(s) * (1.f/16.f) + 1e-6f);
  float4 wv = ((const float4*)w)[lane];
  float4 r;
  r.x = v.x*scale*wv.x; r.y = v.y*scale*wv.y; r.z = v.z*scale*wv.z; r.w = v.w*scale*wv.w;
  if (blockIdx.y == 0){
    ushort4 o; o.x=f2bf(r.x); o.y=f2bf(r.y); o.z=f2bf(r.z); o.w=f2bf(r.w);
    ((ushort4*)(o0b + tok*DD))[lane] = o;
  } else {
    ((float4*)(o1 + tok*DD))[lane] = r;
  }
}

// ---------------- weight fp32->bf16 conversion -----------------------------------
__global__ __launch_bounds__(256) void cvt1_kernel(
    const float* __restrict__ s, unsigned short* __restrict__ d, int n)
{
  int i = blockIdx.x*256 + threadIdx.x;
  if (i < n) d[i] = f2bf(s[i]);
}
__global__ __launch_bounds__(256) void cvt3_kernel(
    const float* __restrict__ s0, const float* __restrict__ s1,
    const float* __restrict__ s2, unsigned short* __restrict__ d)
{
  int i = blockIdx.x*256 + threadIdx.x;   // 0..131071
  float v;
  if (i < 65536)       v = s0[i];
  else if (i < 98304)  v = s1[i - 65536];
  else                 v = s2[i - 98304];
  d[i] = f2bf(v);
}

// ---------------- bf16 MFMA GEMM: C = A @ Bw^T  (+ epilogue) ---------------------
// A: M x K bf16 row-major; Bw: N x K bf16 row-major.
// EPI: 0 = C=acc ; 1 = C=acc+Add & Cb=bf16(C) ; 2 = C=acc+Add ; 3 = Cb=bf16(acc) only
template<int EPI>
__global__ __launch_bounds__(256) void gemm_mfma(
    const unsigned short* __restrict__ A, const unsigned short* __restrict__ Bw,
    float* __restrict__ C, const float* __restrict__ Add,
    unsigned short* __restrict__ Cb, int M, int N, int K)
{
  constexpr int BM = 128, BN = 128, BK = 32, PAD = 8;
  __shared__ __align__(16) unsigned short As[BM][BK+PAD];
  __shared__ __align__(16) unsigned short Bs[BN][BK+PAD];
  int tid  = threadIdx.x;
  int row0 = blockIdx.x * BM;
  int col0 = blockIdx.y * BN;
  int wave = tid >> 6, lane = tid & 63;
  int wm = (wave >> 1) * 64, wn = (wave & 1) * 64;
  int lm = lane & 15, kq = lane >> 4;

  f32x4 acc[4][4];
  #pragma unroll
  for (int i = 0; i < 4; i++)
    #pragma unroll
    for (int j = 0; j < 4; j++) acc[i][j] = (f32x4){0.f,0.f,0.f,0.f};

  for (int k0 = 0; k0 < K; k0 += BK){
    #pragma unroll
    for (int e = tid; e < BM*4; e += 256){
      int r = e >> 2, c8 = (e & 3) * 8;
      *(int4*)&As[r][c8] = *(const int4*)&A[(size_t)(row0 + r)*K + k0 + c8];
    }
    #pragma unroll
    for (int e = tid; e < BN*4; e += 256){
      int r = e >> 2, c8 = (e & 3) * 8;
      *(int4*)&Bs[r][c8] = *(const int4*)&Bw[(size_t)(col0 + r)*K + k0 + c8];
    }
    __syncthreads();
    bf16x8 af[4], bfv[4];
    #pragma unroll
    for (int i = 0; i < 4; i++) af[i] = *(const bf16x8*)&As[wm + i*16 + lm][kq*8];
    #pragma unroll
    for (int j = 0; j < 4; j++) bfv[j] = *(const bf16x8*)&Bs[wn + j*16 + lm][kq*8];
    #pragma unroll
    for (int i = 0; i < 4; i++)
      #pragma unroll
      for (int j = 0; j < 4; j++)
        acc[i][j] = __builtin_amdgcn_mfma_f32_16x16x32_bf16(af[i], bfv[j], acc[i][j], 0, 0, 0);
    __syncthreads();
  }

  // C/D layout: col = lane&15, row = (lane>>4)*4 + reg   [m89-verified]
  #pragma unroll
  for (int i = 0; i < 4; i++){
    int rbase = row0 + wm + i*16 + kq*4;
    #pragma unroll
    for (int j = 0; j < 4; j++){
      int col = col0 + wn + j*16 + lm;
      #pragma unroll
      for (int r = 0; r < 4; r++){
        size_t idx = (size_t)(rbase + r)*N + col;
        float v = acc[i][j][r];
        if constexpr (EPI == 1 || EPI == 2) v += Add[idx];
        if constexpr (EPI != 3) C[idx] = v;
        if constexpr (EPI == 1 || EPI == 3) Cb[idx] = f2bf(v);
      }
    }
  }
}

// ---------------- fp32 GEMM (xproj only) -----------------------------------------
template<int BM, int BN, int BK, int TM, int TN>
__global__ __launch_bounds__(256) void gemm_abt(
    const float* __restrict__ A, const float* __restrict__ Bw,
    float* __restrict__ C, int M, int N, int K, int lda, int flipA)
{
  __shared__ __align__(16) float As[BK][BM+4];
  __shared__ __align__(16) float Bs[BK][BN+4];
  int tid = threadIdx.x;
  int row0 = blockIdx.x * BM;
  int col0 = blockIdx.y * BN;
  int tr = tid / (BN/TN);
  int tc = tid % (BN/TN);
  float acc[TM][TN];
  #pragma unroll
  for (int i = 0; i < TM; i++)
    #pragma unroll
    for (int j = 0; j < TN; j++) acc[i][j] = 0.f;

  for (int k0 = 0; k0 < K; k0 += BK){
    #pragma unroll
    for (int e = tid; e < BM*BK; e += 256){
      int r = e / BK, c = e % BK;
      int pr = row0 + r;
      if (flipA){ int b = pr / LL; int t = pr % LL; pr = b*LL + (LL-1-t); }
      As[c][r] = A[(size_t)pr*lda + k0 + c];
    }
    #pragma unroll
    for (int e = tid; e < BN*BK; e += 256){
      int r = e / BK, c = e % BK;
      Bs[c][r] = Bw[(size_t)(col0 + r)*K + k0 + c];
    }
    __syncthreads();
    #pragma unroll
    for (int kk = 0; kk < BK; kk++){
      float a[TM], bfv[TN];
      #pragma unroll
      for (int i = 0; i < TM; i++) a[i] = As[kk][tr*TM + i];
      #pragma unroll
      for (int j = 0; j < TN; j++) bfv[j] = Bs[kk][tc*TN + j];
      #pragma unroll
      for (int i = 0; i < TM; i++)
        #pragma unroll
        for (int j = 0; j < TN; j++) acc[i][j] = fmaf(a[i], bfv[j], acc[i][j]);
    }
    __syncthreads();
  }

  #pragma unroll
  for (int i = 0; i < TM; i++){
    int r = row0 + tr*TM + i;
    size_t base = (size_t)r*N + col0 + tc*TN;
    #pragma unroll
    for (int j = 0; j < TN; j++) C[base + j] = acc[i][j];
  }
}

// =================== Fused chunk-parallel selective scan =========================
// conv(k=4,causal)+silu and delta=softplus(dt@dtw+b) computed inline from bf16 xin
// and the x_dbl LDS tile. thread = one d; block = (chunk, b, dir).
// Carry layout: [dir][chunk][b][d][n], 2*64*4*2048 floats.

__device__ __forceinline__ float load_xin(
    const unsigned short* __restrict__ xin, int b, int dir, int pos, int d)
{
  if (pos < 0) return 0.f;
  int src = dir ? (LL-1-pos) : pos;
  return bf2f(xin[((size_t)b*LL + src)*DD + d]);
}

template<int PHASE>   // 1 = emit P,Hout ; 3 = seeded, emit y
__global__ __launch_bounds__(256) void scan_fused(
    const unsigned short* __restrict__ xin,
    const float* __restrict__ xdf, const float* __restrict__ xdb,
    const float* __restrict__ cwf, const float* __restrict__ cbf,
    const float* __restrict__ cwb, const float* __restrict__ cbb,
    const float* __restrict__ dtwf, const float* __restrict__ dtbf,
    const float* __restrict__ dtwb, const float* __restrict__ dtbb,
    const float* __restrict__ Alogf, const float* __restrict__ Alogb,
    const float* __restrict__ Dfp, const float* __restrict__ Dbp,
    float* __restrict__ P, float* __restrict__ Hout,      // phase 1 outputs
    const float* __restrict__ Hin,                        // phase 3 input
    float* __restrict__ yf, float* __restrict__ yb)       // phase 3 outputs
{
  int chunk = blockIdx.x, b = blockIdx.y, dir = blockIdx.z;
  const float* xd   = dir ? xdb : xdf;
  const float* Alog = dir ? Alogb : Alogf;
  int d = threadIdx.x;

  __shared__ float sXD[CLEN*32];
  {
    const float* xdp = xd + ((size_t)b*LL + (size_t)chunk*CLEN)*32;
    #pragma unroll
    for (int e = threadIdx.x; e < CLEN*32; e += 256) sXD[e] = xdp[e];
  }
  __syncthreads();

  // per-thread params
  float4 cw = ((const float4*)(dir ? cwb : cwf))[d];
  float cb  = (dir ? cbb : cbf)[d];
  float dtb = (dir ? dtbb : dtbf)[d];
  float4 dtw0 = ((const float4*)((dir ? dtwb : dtwf) + d*RANK))[0];
  float4 dtw1 = ((const float4*)((dir ? dtwb : dtwf) + d*RANK))[1];
  float4 dtw2 = ((const float4*)((dir ? dtwb : dtwf) + d*RANK))[2];
  float4 dtw3 = ((const float4*)((dir ? dtwb : dtwf) + d*RANK))[3];
  float A[NST];
  #pragma unroll
  for (int n = 0; n < NST; n++) A[n] = -__expf(Alog[d*NST + n]);

  float h[NST];
  float Dd = 0.f, S = 0.f;
  if constexpr (PHASE == 1){
    #pragma unroll
    for (int n = 0; n < NST; n++) h[n] = 0.f;
  } else {
    Dd = (dir ? Dbp : Dfp)[d];
    size_t ib = ((((size_t)dir*CH + chunk)*BB + b)*DD + d)*NST;
    float4 a0 = *(const float4*)&Hin[ib];
    float4 a1 = *(const float4*)&Hin[ib+4];
    h[0]=a0.x; h[1]=a0.y; h[2]=a0.z; h[3]=a0.w;
    h[4]=a1.x; h[5]=a1.y; h[6]=a1.z; h[7]=a1.w;
  }

  int base = chunk*CLEN;
  float* yp = nullptr;
  if constexpr (PHASE == 3)
    yp = (dir ? yb : yf) + ((size_t)b*LL + base)*DD + d;

  // conv pipeline registers (scan-order positions base-3..base-1)
  float x3 = load_xin(xin, b, dir, base-3, d);
  float x2 = load_xin(xin, b, dir, base-2, d);
  float x1 = load_xin(xin, b, dir, base-1, d);

  const int U = 8;
  float px[U];
  #pragma unroll
  for (int u = 0; u < U; u++) px[u] = load_xin(xin, b, dir, base+u, d);

  for (int t0 = 0; t0 < CLEN; t0 += U){
    float nx[U];
    if (t0 + U < CLEN){
      #pragma unroll
      for (int u = 0; u < U; u++) nx[u] = load_xin(xin, b, dir, base+t0+U+u, d);
    }
    #pragma unroll
    for (int u = 0; u < U; u++){
      int t = t0 + u;
      // causal depthwise conv + silu
      float xc = cb;
      xc = fmaf(cw.x, x3, xc); xc = fmaf(cw.y, x2, xc);
      xc = fmaf(cw.z, x1, xc); xc = fmaf(cw.w, px[u], xc);
      xc = siluf(xc);
      x3 = x2; x2 = x1; x1 = px[u];
      // delta = softplus(dt . dtw + b)
      const float4 dt0 = *(const float4*)&sXD[t*32 + 0];
      const float4 dt1 = *(const float4*)&sXD[t*32 + 4];
      const float4 dt2 = *(const float4*)&sXD[t*32 + 8];
      const float4 dt3 = *(const float4*)&sXD[t*32 + 12];
      float de = dtb;
      de = fmaf(dt0.x,dtw0.x, fmaf(dt0.y,dtw0.y, fmaf(dt0.z,dtw0.z, fmaf(dt0.w,dtw0.w, de))));
      de = fmaf(dt1.x,dtw1.x, fmaf(dt1.y,dtw1.y, fmaf(dt1.z,dtw1.z, fmaf(dt1.w,dtw1.w, de))));
      de = fmaf(dt2.x,dtw2.x, fmaf(dt2.y,dtw2.y, fmaf(dt2.z,dtw2.z, fmaf(dt2.w,dtw2.w, de))));
      de = fmaf(dt3.x,dtw3.x, fmaf(dt3.y,dtw3.y, fmaf(dt3.z,dtw3.z, fmaf(dt3.w,dtw3.w, de))));
      de = softplusf_(de);
      float dux = de * xc;
      const float4 Bv0 = *(const float4*)&sXD[t*32 + 16];
      const float4 Bv1 = *(const float4*)&sXD[t*32 + 20];
      if constexpr (PHASE == 1){
        S += de;
        h[0] = fmaf(__expf(de*A[0]), h[0], dux*Bv0.x);
        h[1] = fmaf(__expf(de*A[1]), h[1], dux*Bv0.y);
        h[2] = fmaf(__expf(de*A[2]), h[2], dux*Bv0.z);
        h[3] = fmaf(__expf(de*A[3]), h[3], dux*Bv0.w);
        h[4] = fmaf(__expf(de*A[4]), h[4], dux*Bv1.x);
        h[5] = fmaf(__expf(de*A[5]), h[5], dux*Bv1.y);
        h[6] = fmaf(__expf(de*A[6]), h[6], dux*Bv1.z);
        h[7] = fmaf(__expf(de*A[7]), h[7], dux*Bv1.w);
      } else {
        const float4 Cv0 = *(const float4*)&sXD[t*32 + 24];
        const float4 Cv1 = *(const float4*)&sXD[t*32 + 28];
        float acc = xc * Dd;
        h[0] = fmaf(__expf(de*A[0]), h[0], dux*Bv0.x); acc = fmaf(h[0], Cv0.x, acc);
        h[1] = fmaf(__expf(de*A[1]), h[1], dux*Bv0.y); acc = fmaf(h[1], Cv0.y, acc);
        h[2] = fmaf(__expf(de*A[2]), h[2], dux*Bv0.z); acc = fmaf(h[2], Cv0.z, acc);
        h[3] = fmaf(__expf(de*A[3]), h[3], dux*Bv0.w); acc = fmaf(h[3], Cv0.w, acc);
        h[4] = fmaf(__expf(de*A[4]), h[4], dux*Bv1.x); acc = fmaf(h[4], Cv1.x, acc);
        h[5] = fmaf(__expf(de*A[5]), h[5], dux*Bv1.y); acc = fmaf(h[5], Cv1.y, acc);
        h[6] = fmaf(__expf(de*A[6]), h[6], dux*Bv1.z); acc = fmaf(h[6], Cv1.z, acc);
        h[7] = fmaf(__expf(de*A[7]), h[7], dux*Bv1.w); acc = fmaf(h[7], Cv1.w, acc);
        yp[(size_t)t*DD] = acc;
      }
    }
    if (t0 + U < CLEN){
      #pragma unroll
      for (int u = 0; u < U; u++) px[u] = nx[u];
    }
  }

  if constexpr (PHASE == 1){
    size_t ob = ((((size_t)dir*CH + chunk)*BB + b)*DD + d)*NST;
    float4 p0, p1h, h0v, h1v;
    p0.x = __expf(A[0]*S); p0.y = __expf(A[1]*S); p0.z = __expf(A[2]*S); p0.w = __expf(A[3]*S);
    p1h.x= __expf(A[4]*S); p1h.y= __expf(A[5]*S); p1h.z= __expf(A[6]*S); p1h.w= __expf(A[7]*S);
    h0v.x=h[0]; h0v.y=h[1]; h0v.z=h[2]; h0v.w=h[3];
    h1v.x=h[4]; h1v.y=h[5]; h1v.z=h[6]; h1v.w=h[7];
    *(float4*)&P[ob]      = p0;  *(float4*)&P[ob+4]    = p1h;
    *(float4*)&Hout[ob]   = h0v; *(float4*)&Hout[ob+4] = h1v;
  }
}

__global__ __launch_bounds__(256) void scan_p2(
    const float* __restrict__ P, const float* __restrict__ Hout,
    float* __restrict__ Hin)
{
  int tid = blockIdx.x*256 + threadIdx.x;   // 0..16383
  int dir = tid >> 13;
  int b   = (tid >> 11) & 3;
  int dn  = tid & 2047;
  float h = 0.f;
  #pragma unroll 8
  for (int c = 0; c < CH; c++){
    size_t idx = (((size_t)dir*CH + c)*BB + b)*2048 + dn;
    Hin[idx] = h;
    h = fmaf(P[idx], h, Hout[idx]);
  }
}

// ---------------- Combine: y=(yf+flip(yb))/2 -> rmsnorm -> *silu(z) -> bf16 ------
__global__ __launch_bounds__(64) void combine_kernel(
    const float* __restrict__ yf, const float* __restrict__ yb,
    const unsigned short* __restrict__ zb, const float* __restrict__ wn,
    unsigned short* __restrict__ outb)
{
  size_t tok = blockIdx.x;
  int b = (int)(tok / LL), t = (int)(tok % LL);
  int lane = threadIdx.x;
  float4 a = ((const float4*)(yf + tok*DD))[lane];
  float4 c = ((const float4*)(yb + ((size_t)b*LL + (LL-1-t))*DD))[lane];
  float4 v;
  v.x=(a.x+c.x)*0.5f; v.y=(a.y+c.y)*0.5f; v.z=(a.z+c.z)*0.5f; v.w=(a.w+c.w)*0.5f;
  float s = v.x*v.x + v.y*v.y + v.z*v.z + v.w*v.w;
  #pragma unroll
  for (int m = 1; m < 64; m <<= 1) s += __shfl_xor(s, m, 64);
  float scale = 1.f / (sqrtf(s)*(1.f/16.f) + 1e-6f);
  float4 wv = ((const float4*)wn)[lane];
  ushort4 zv = ((const ushort4*)(zb + tok*DD))[lane];
  ushort4 r;
  r.x = f2bf(v.x*scale*wv.x*siluf(bf2f(zv.x)));
  r.y = f2bf(v.y*scale*wv.y*siluf(bf2f(zv.y)));
  r.z = f2bf(v.z*scale*wv.z*siluf(bf2f(zv.z)));
  r.w = f2bf(v.w*scale*wv.w*siluf(bf2f(zv.w)));
  ((ushort4*)(outb + tok*DD))[lane] = r;
}

// ---------------- FF depthwise conv k=3 pad(1,1) + SiLU -> bf16 ------------------
__global__ __launch_bounds__(256) void dwconv3_kernel(
    const float* __restrict__ m, const float* __restrict__ w,
    const float* __restrict__ bi, unsigned short* __restrict__ o)
{
  size_t gid = (size_t)blockIdx.x*256 + threadIdx.x;  // over BL*HID
  int c = (int)(gid % HID);
  int tok = (int)(gid / HID);
  int b = tok / LL, t = tok % LL;
  float acc = bi[c];
  #pragma unroll
  for (int k = 0; k < 3; k++){
    int tt = t - 1 + k;
    if (tt >= 0 && tt < LL)
      acc = fmaf(w[c*3 + k], m[((size_t)b*LL + tt)*HID + c], acc);
  }
  o[gid] = f2bf(siluf(acc));
}

extern "C" void kernel_launch(void* const* d_in, const int* in_sizes, int n_in,
                              void* d_out, int out_size, void* d_ws, size_t ws_size,
                              hipStream_t stream)
{
  const float* x0        = (const float*)d_in[0];
  const float* x1        = (const float*)d_in[1];
  const float* w_norm0   = (const float*)d_in[2];
  const float* w_norm1   = (const float*)d_in[3];
  const float* in_proj_w = (const float*)d_in[4];
  const float* conv_w_f  = (const float*)d_in[5];
  const float* conv_b_f  = (const float*)d_in[6];
  const float* xproj_w_f = (const float*)d_in[7];
  const float* dtproj_w_f= (const float*)d_in[8];
  const float* dtproj_b_f= (const float*)d_in[9];
  const float* A_log_f   = (const float*)d_in[10];
  const float* D_f       = (const float*)d_in[11];
  const float* conv_w_bw = (const float*)d_in[12];
  const float* conv_b_bw = (const float*)d_in[13];
  const float* xproj_w_bw= (const float*)d_in[14];
  const float* dtproj_w_bw=(const float*)d_in[15];
  const float* dtproj_b_bw=(const float*)d_in[16];
  const float* A_log_bw  = (const float*)d_in[17];
  const float* D_bw      = (const float*)d_in[18];
  const float* norm_y_w  = (const float*)d_in[19];
  const float* out_proj_w= (const float*)d_in[20];
  const float* fc1_w     = (const float*)d_in[21];
  const float* dw_w      = (const float*)d_in[22];
  const float* dw_b      = (const float*)d_in[23];
  const float* fc2_w     = (const float*)d_in[24];
  float* out = (float*)d_out;
  float* ws  = (float*)d_ws;

  // region map (floats), lifetime-reused
  float* r0 = ws + 0*BLD;   // h0b (bf16) -> yfv (fp32)
  float* r1 = ws + 1*BLD;   // h1 (fp32)  -> ybv (fp32)
  float* r2 = ws + 2*BLD;   // xin_b (bf16, live until p3) -> ycomb_b (bf16)
  float* r3 = ws + 3*BLD;   // zb (bf16, live until combine)
  float* r4 = ws + 4*BLD;   // scan carries (12 MB) -> m1 (fp32)
  float* r5 = ws + 5*BLD;   // m2b (bf16)
  float* r6 = ws + 6*BLD;   // wbuf1 (bf16 in_proj weights)
  float* r7 = ws + 7*BLD;   // wbuf2 (bf16 out/fc1/fc2 weights) + xb (bf16)
  float* xdf  = ws + 8*BLD;            // BL*32
  float* xdb  = ws + 8*BLD + (size_t)BL*32;

  unsigned short* h0b   = (unsigned short*)r0;
  float*          h1    = r1;
  unsigned short* xin_b = (unsigned short*)r2;
  unsigned short* zb    = (unsigned short*)r3;
  unsigned short* wbuf1 = (unsigned short*)r6;   // 131072
  float*          yfv   = r0;
  float*          ybv   = r1;
  const size_t CARRY = (size_t)2*CH*BB*DD*NST;   // 1,048,576 floats
  float* Pbuf = r4;
  float* Hout = r4 + CARRY;
  float* Hin  = r4 + 2*CARRY;
  unsigned short* ycomb_b = (unsigned short*)r2;
  unsigned short* wbuf2   = (unsigned short*)r7;
  unsigned short* wb_out  = wbuf2;            // 65536
  unsigned short* wb_fc1  = wbuf2 + 65536;    // 32768
  unsigned short* wb_fc2  = wbuf2 + 98304;    // 32768
  unsigned short* xb      = wbuf2 + 131072;   // BLD bf16
  float*          m1      = r4;
  unsigned short* m2b     = (unsigned short*)r5;

  // 0. weight conversions (independent)
  cvt1_kernel<<<dim3(512), 256, 0, stream>>>(in_proj_w, wbuf1, 131072);
  cvt3_kernel<<<dim3(512), 256, 0, stream>>>(out_proj_w, fc1_w, fc2_w, wbuf2);

  // 1. RMSNorm x0 -> h0b (bf16), x1 -> h1 (fp32)
  rms_kernel<<<dim3(BL,2), 64, 0, stream>>>(x0, w_norm0, h0b, x1, w_norm1, h1);

  // 2. xz = h0 @ in_proj_w.T -> xin_b (bf16), zb (bf16)
  gemm_mfma<3><<<dim3(BL/128, 2), 256, 0, stream>>>(
      h0b, wbuf1, nullptr, nullptr, xin_b, BL, 256, 256);
  gemm_mfma<3><<<dim3(BL/128, 2), 256, 0, stream>>>(
      h0b, wbuf1 + 65536, nullptr, nullptr, zb, BL, 256, 256);

  // 3. x_dbl = ctx @ xproj.T (fp32; forward h1, backward flipped h1)
  gemm_abt<64,32,16,4,2><<<dim3(BL/64,1), 256, 0, stream>>>(
      h1, xproj_w_f, xdf, BL, 32, 256, 256, 0);
  gemm_abt<64,32,16,4,2><<<dim3(BL/64,1), 256, 0, stream>>>(
      h1, xproj_w_bw, xdb, BL, 32, 256, 256, 1);

  // 4-6. fused conv+delta+scan, chunk-parallel
  scan_fused<1><<<dim3(CH,BB,2), 256, 0, stream>>>(
      xin_b, xdf, xdb, conv_w_f, conv_b_f, conv_w_bw, conv_b_bw,
      dtproj_w_f, dtproj_b_f, dtproj_w_bw, dtproj_b_bw,
      A_log_f, A_log_bw, D_f, D_bw, Pbuf, Hout, nullptr, nullptr, nullptr);
  scan_p2<<<dim3(64), 256, 0, stream>>>(Pbuf, Hout, Hin);
  scan_fused<3><<<dim3(CH,BB,2), 256, 0, stream>>>(
      xin_b, xdf, xdb, conv_w_f, conv_b_f, conv_w_bw, conv_b_bw,
      dtproj_w_f, dtproj_b_f, dtproj_w_bw, dtproj_b_bw,
      A_log_f, A_log_bw, D_f, D_bw, nullptr, nullptr, Hin, yfv, ybv);

  // 7. combine + rmsnorm + gate -> bf16 (r2; xin dead)
  combine_kernel<<<dim3(BL), 64, 0, stream>>>(yfv, ybv, zb, norm_y_w, ycomb_b);

  // 8. x = y @ out_proj.T + residual(x0) -> d_out (fp32) + xb (bf16)
  gemm_mfma<1><<<dim3(BL/128, 2), 256, 0, stream>>>(
      ycomb_b, wb_out, out, x0, xb, BL, 256, 256);

  // 9. m1 = x @ fc1.T (fp32; overwrites dead carries)
  gemm_mfma<0><<<dim3(BL/128, 1), 256, 0, stream>>>(
      xb, wb_fc1, m1, nullptr, nullptr, BL, 128, 256);

  // 10. m2 = silu(dwconv3(m1)) -> bf16
  dwconv3_kernel<<<dim3((BL*HID)/256), 256, 0, stream>>>(m1, dw_w, dw_b, m2b);

  // 11. out = x + m2 @ fc2.T
  gemm_mfma<2><<<dim3(BL/128, 2), 256, 0, stream>>>(
      m2b, wb_fc2, out, out, nullptr, BL, 256, 128);
}

// Round 5
// 323.908 us; speedup vs baseline: 1.1893x; 1.1893x over previous
//
#include <hip/hip_runtime.h>
#include <math.h>
#include <cstddef>

#define BB 4
#define LL 4096
#define DD 256
#define NST 8
#define RANK 16
#define HID 128
#define BL (BB*LL)          // 16384
#define BLD ((size_t)BL*DD) // 4194304
#define CH 128              // scan chunks
#define CLEN 32             // steps per chunk (CH*CLEN == LL)

typedef __bf16 bf16x8 __attribute__((ext_vector_type(8)));
typedef float  f32x4  __attribute__((ext_vector_type(4)));

__device__ __forceinline__ float siluf(float x){ return x / (1.f + __expf(-x)); }
// fast softplus: log1pf libcall is slow; __logf(1+__expf) is 2 trans + 2 VALU
__device__ __forceinline__ float softplus_fast(float x){
  float r = __logf(1.f + __expf(x));
  return x > 15.f ? x : r;
}
// fp32 -> bf16 bits, round-to-nearest-even
__device__ __forceinline__ unsigned short f2bf(float x){
  union { float f; unsigned u; } v; v.f = x;
  unsigned r = v.u + 0x7fffu + ((v.u >> 16) & 1u);
  return (unsigned short)(r >> 16);
}
__device__ __forceinline__ float bf2f(unsigned short u){
  union { unsigned u32; float f; } c; c.u32 = ((unsigned)u) << 16;
  return c.f;
}

// ---------------- RMSNorm: h0 -> bf16, h1 -> fp32 --------------------------------
__global__ __launch_bounds__(64) void rms_kernel(
    const float* __restrict__ x0, const float* __restrict__ w0, unsigned short* __restrict__ o0b,
    const float* __restrict__ x1, const float* __restrict__ w1, float* __restrict__ o1)
{
  const float* x; const float* w;
  if (blockIdx.y == 0){ x = x0; w = w0; } else { x = x1; w = w1; }
  size_t tok = blockIdx.x;
  int lane = threadIdx.x;
  float4 v = ((const float4*)(x + tok*DD))[lane];
  float s = v.x*v.x + v.y*v.y + v.z*v.z + v.w*v.w;
  #pragma unroll
  for (int m = 1; m < 64; m <<= 1) s += __shfl_xor(s, m, 64);
  float scale = 1.f / (sqrtf(s) * (1.f/16.f) + 1e-6f);
  float4 wv = ((const float4*)w)[lane];
  float4 r;
  r.x = v.x*scale*wv.x; r.y = v.y*scale*wv.y; r.z = v.z*scale*wv.z; r.w = v.w*scale*wv.w;
  if (blockIdx.y == 0){
    ushort4 o; o.x=f2bf(r.x); o.y=f2bf(r.y); o.z=f2bf(r.z); o.w=f2bf(r.w);
    ((ushort4*)(o0b + tok*DD))[lane] = o;
  } else {
    ((float4*)(o1 + tok*DD))[lane] = r;
  }
}

// ---------------- weight fp32->bf16 conversion -----------------------------------
__global__ __launch_bounds__(256) void cvt1_kernel(
    const float* __restrict__ s, unsigned short* __restrict__ d, int n)
{
  int i = blockIdx.x*256 + threadIdx.x;
  if (i < n) d[i] = f2bf(s[i]);
}
__global__ __launch_bounds__(256) void cvt3_kernel(
    const float* __restrict__ s0, const float* __restrict__ s1,
    const float* __restrict__ s2, unsigned short* __restrict__ d)
{
  int i = blockIdx.x*256 + threadIdx.x;   // 0..131071
  float v;
  if (i < 65536)       v = s0[i];
  else if (i < 98304)  v = s1[i - 65536];
  else                 v = s2[i - 98304];
  d[i] = f2bf(v);
}

// ---------------- bf16 MFMA GEMM, 64x64 tile: C = A @ Bw^T (+ epilogue) ----------
// A: M x K bf16 row-major; Bw: N x K bf16 row-major.
// EPI: 0 = C=acc ; 1 = C=acc+Add & Cb=bf16(C) ; 2 = C=acc+Add ; 3 = Cb=bf16(acc)
template<int EPI>
__global__ __launch_bounds__(256) void gemm_mfma(
    const unsigned short* __restrict__ A, const unsigned short* __restrict__ Bw,
    float* __restrict__ C, const float* __restrict__ Add,
    unsigned short* __restrict__ Cb, int M, int N, int K)
{
  constexpr int BK = 32, PAD = 8;
  __shared__ __align__(16) unsigned short As[64][BK+PAD];
  __shared__ __align__(16) unsigned short Bs[64][BK+PAD];
  int tid  = threadIdx.x;
  int row0 = blockIdx.x * 64;
  int col0 = blockIdx.y * 64;
  int wave = tid >> 6, lane = tid & 63;
  int wm = (wave >> 1) * 32, wn = (wave & 1) * 32;
  int lm = lane & 15, kq = lane >> 4;
  int sr = tid >> 2, sc8 = (tid & 3) * 8;   // one 16B stage chunk per thread

  f32x4 acc[2][2];
  #pragma unroll
  for (int i = 0; i < 2; i++)
    #pragma unroll
    for (int j = 0; j < 2; j++) acc[i][j] = (f32x4){0.f,0.f,0.f,0.f};

  for (int k0 = 0; k0 < K; k0 += BK){
    *(int4*)&As[sr][sc8] = *(const int4*)&A [(size_t)(row0 + sr)*K + k0 + sc8];
    *(int4*)&Bs[sr][sc8] = *(const int4*)&Bw[(size_t)(col0 + sr)*K + k0 + sc8];
    __syncthreads();
    bf16x8 af[2], bfv[2];
    #pragma unroll
    for (int i = 0; i < 2; i++) af[i]  = *(const bf16x8*)&As[wm + i*16 + lm][kq*8];
    #pragma unroll
    for (int j = 0; j < 2; j++) bfv[j] = *(const bf16x8*)&Bs[wn + j*16 + lm][kq*8];
    #pragma unroll
    for (int i = 0; i < 2; i++)
      #pragma unroll
      for (int j = 0; j < 2; j++)
        acc[i][j] = __builtin_amdgcn_mfma_f32_16x16x32_bf16(af[i], bfv[j], acc[i][j], 0, 0, 0);
    __syncthreads();
  }

  // C/D layout: col = lane&15, row = (lane>>4)*4 + reg   [m89-verified]
  #pragma unroll
  for (int i = 0; i < 2; i++){
    int rbase = row0 + wm + i*16 + kq*4;
    #pragma unroll
    for (int j = 0; j < 2; j++){
      int col = col0 + wn + j*16 + lm;
      #pragma unroll
      for (int r = 0; r < 4; r++){
        size_t idx = (size_t)(rbase + r)*N + col;
        float v = acc[i][j][r];
        if constexpr (EPI == 1 || EPI == 2) v += Add[idx];
        if constexpr (EPI != 3) C[idx] = v;
        if constexpr (EPI == 1 || EPI == 3) Cb[idx] = f2bf(v);
      }
    }
  }
}

// ---------------- fp32 GEMM (xproj only) -----------------------------------------
template<int BM, int BN, int BK, int TM, int TN>
__global__ __launch_bounds__(256) void gemm_abt(
    const float* __restrict__ A, const float* __restrict__ Bw,
    float* __restrict__ C, int M, int N, int K, int lda, int flipA)
{
  __shared__ __align__(16) float As[BK][BM+4];
  __shared__ __align__(16) float Bs[BK][BN+4];
  int tid = threadIdx.x;
  int row0 = blockIdx.x * BM;
  int col0 = blockIdx.y * BN;
  int tr = tid / (BN/TN);
  int tc = tid % (BN/TN);
  float acc[TM][TN];
  #pragma unroll
  for (int i = 0; i < TM; i++)
    #pragma unroll
    for (int j = 0; j < TN; j++) acc[i][j] = 0.f;

  for (int k0 = 0; k0 < K; k0 += BK){
    #pragma unroll
    for (int e = tid; e < BM*BK; e += 256){
      int r = e / BK, c = e % BK;
      int pr = row0 + r;
      if (flipA){ int b = pr / LL; int t = pr % LL; pr = b*LL + (LL-1-t); }
      As[c][r] = A[(size_t)pr*lda + k0 + c];
    }
    #pragma unroll
    for (int e = tid; e < BN*BK; e += 256){
      int r = e / BK, c = e % BK;
      Bs[c][r] = Bw[(size_t)(col0 + r)*K + k0 + c];
    }
    __syncthreads();
    #pragma unroll
    for (int kk = 0; kk < BK; kk++){
      float a[TM], bfv[TN];
      #pragma unroll
      for (int i = 0; i < TM; i++) a[i] = As[kk][tr*TM + i];
      #pragma unroll
      for (int j = 0; j < TN; j++) bfv[j] = Bs[kk][tc*TN + j];
      #pragma unroll
      for (int i = 0; i < TM; i++)
        #pragma unroll
        for (int j = 0; j < TN; j++) acc[i][j] = fmaf(a[i], bfv[j], acc[i][j]);
    }
    __syncthreads();
  }

  #pragma unroll
  for (int i = 0; i < TM; i++){
    int r = row0 + tr*TM + i;
    size_t base = (size_t)r*N + col0 + tc*TN;
    #pragma unroll
    for (int j = 0; j < TN; j++) C[base + j] = acc[i][j];
  }
}

// =================== Chunk-parallel selective scan ===============================
// Phase 1 computes conv+silu (xc) and delta (softplus) inline, packs them as
// bf16x2 into xde for phase 3, runs local scan from h=0 -> P, Hout.
// thread = one d; block = (chunk, b, dir). Carry layout [dir][chunk][b][d][n].

__device__ __forceinline__ float load_xin(
    const unsigned short* __restrict__ xin, int b, int dir, int pos, int d)
{
  if (pos < 0) return 0.f;
  int src = dir ? (LL-1-pos) : pos;
  return bf2f(xin[((size_t)b*LL + src)*DD + d]);
}

__global__ __launch_bounds__(256) void scan_p1(
    const unsigned short* __restrict__ xin,
    const float* __restrict__ xdf, const float* __restrict__ xdb,
    const float* __restrict__ cwf, const float* __restrict__ cbf,
    const float* __restrict__ cwb, const float* __restrict__ cbb,
    const float* __restrict__ dtwf, const float* __restrict__ dtbf,
    const float* __restrict__ dtwb, const float* __restrict__ dtbb,
    const float* __restrict__ Alogf, const float* __restrict__ Alogb,
    unsigned int* __restrict__ xde,
    float* __restrict__ P, float* __restrict__ Hout)
{
  int chunk = blockIdx.x, b = blockIdx.y, dir = blockIdx.z;
  const float* xd   = dir ? xdb : xdf;
  const float* Alog = dir ? Alogb : Alogf;
  int d = threadIdx.x;

  __shared__ float sXD[CLEN*32];   // 4 KB
  {
    const float* xdp = xd + ((size_t)b*LL + (size_t)chunk*CLEN)*32;
    #pragma unroll
    for (int e = threadIdx.x; e < CLEN*32; e += 256) sXD[e] = xdp[e];
  }
  __syncthreads();

  float4 cw = ((const float4*)(dir ? cwb : cwf))[d];
  float cb  = (dir ? cbb : cbf)[d];
  float dtb = (dir ? dtbb : dtbf)[d];
  const float* dtw = (dir ? dtwb : dtwf) + d*RANK;
  float4 dtw0 = ((const float4*)dtw)[0];
  float4 dtw1 = ((const float4*)dtw)[1];
  float4 dtw2 = ((const float4*)dtw)[2];
  float4 dtw3 = ((const float4*)dtw)[3];
  float A[NST];
  #pragma unroll
  for (int n = 0; n < NST; n++) A[n] = -__expf(Alog[d*NST + n]);

  float h[NST];
  #pragma unroll
  for (int n = 0; n < NST; n++) h[n] = 0.f;
  float S = 0.f;

  int base = chunk*CLEN;
  unsigned int* xdep = xde + ((size_t)(dir*BB + b)*LL + base)*DD + d;

  float x3 = load_xin(xin, b, dir, base-3, d);
  float x2 = load_xin(xin, b, dir, base-2, d);
  float x1 = load_xin(xin, b, dir, base-1, d);

  const int U = 8;
  float px[U];
  #pragma unroll
  for (int u = 0; u < U; u++) px[u] = load_xin(xin, b, dir, base+u, d);

  for (int t0 = 0; t0 < CLEN; t0 += U){
    float nx[U];
    if (t0 + U < CLEN){
      #pragma unroll
      for (int u = 0; u < U; u++) nx[u] = load_xin(xin, b, dir, base+t0+U+u, d);
    }
    #pragma unroll
    for (int u = 0; u < U; u++){
      int t = t0 + u;
      float xc = cb;
      xc = fmaf(cw.x, x3, xc); xc = fmaf(cw.y, x2, xc);
      xc = fmaf(cw.z, x1, xc); xc = fmaf(cw.w, px[u], xc);
      xc = siluf(xc);
      x3 = x2; x2 = x1; x1 = px[u];
      const float4 dt0 = *(const float4*)&sXD[t*32 + 0];
      const float4 dt1 = *(const float4*)&sXD[t*32 + 4];
      const float4 dt2 = *(const float4*)&sXD[t*32 + 8];
      const float4 dt3 = *(const float4*)&sXD[t*32 + 12];
      float de = dtb;
      de = fmaf(dt0.x,dtw0.x, fmaf(dt0.y,dtw0.y, fmaf(dt0.z,dtw0.z, fmaf(dt0.w,dtw0.w, de))));
      de = fmaf(dt1.x,dtw1.x, fmaf(dt1.y,dtw1.y, fmaf(dt1.z,dtw1.z, fmaf(dt1.w,dtw1.w, de))));
      de = fmaf(dt2.x,dtw2.x, fmaf(dt2.y,dtw2.y, fmaf(dt2.z,dtw2.z, fmaf(dt2.w,dtw2.w, de))));
      de = fmaf(dt3.x,dtw3.x, fmaf(dt3.y,dtw3.y, fmaf(dt3.z,dtw3.z, fmaf(dt3.w,dtw3.w, de))));
      de = softplus_fast(de);
      xdep[(size_t)t*DD] = (unsigned)f2bf(xc) | ((unsigned)f2bf(de) << 16);
      S += de;
      float dux = de * xc;
      const float4 Bv0 = *(const float4*)&sXD[t*32 + 16];
      const float4 Bv1 = *(const float4*)&sXD[t*32 + 20];
      h[0] = fmaf(__expf(de*A[0]), h[0], dux*Bv0.x);
      h[1] = fmaf(__expf(de*A[1]), h[1], dux*Bv0.y);
      h[2] = fmaf(__expf(de*A[2]), h[2], dux*Bv0.z);
      h[3] = fmaf(__expf(de*A[3]), h[3], dux*Bv0.w);
      h[4] = fmaf(__expf(de*A[4]), h[4], dux*Bv1.x);
      h[5] = fmaf(__expf(de*A[5]), h[5], dux*Bv1.y);
      h[6] = fmaf(__expf(de*A[6]), h[6], dux*Bv1.z);
      h[7] = fmaf(__expf(de*A[7]), h[7], dux*Bv1.w);
    }
    if (t0 + U < CLEN){
      #pragma unroll
      for (int u = 0; u < U; u++) px[u] = nx[u];
    }
  }

  size_t ob = ((((size_t)dir*CH + chunk)*BB + b)*DD + d)*NST;
  float4 p0, p1h, h0v, h1v;
  p0.x = __expf(A[0]*S); p0.y = __expf(A[1]*S); p0.z = __expf(A[2]*S); p0.w = __expf(A[3]*S);
  p1h.x= __expf(A[4]*S); p1h.y= __expf(A[5]*S); p1h.z= __expf(A[6]*S); p1h.w= __expf(A[7]*S);
  h0v.x=h[0]; h0v.y=h[1]; h0v.z=h[2]; h0v.w=h[3];
  h1v.x=h[4]; h1v.y=h[5]; h1v.z=h[6]; h1v.w=h[7];
  *(float4*)&P[ob]      = p0;  *(float4*)&P[ob+4]    = p1h;
  *(float4*)&Hout[ob]   = h0v; *(float4*)&Hout[ob+4] = h1v;
}

// Phase 2: sequential carry over CH chunks. NOTE: Hin aliases P (read-then-write).
__global__ __launch_bounds__(256) void scan_p2(
    const float* P, const float* __restrict__ Hout, float* Hin)
{
  int tid = blockIdx.x*256 + threadIdx.x;   // 0..16383
  int dir = tid >> 13;
  int b   = (tid >> 11) & 3;
  int dn  = tid & 2047;
  float h = 0.f;
  #pragma unroll 8
  for (int c = 0; c < CH; c++){
    size_t idx = (((size_t)dir*CH + c)*BB + b)*2048 + dn;
    float p  = P[idx];
    float ho = Hout[idx];
    Hin[idx] = h;
    h = fmaf(p, h, ho);
  }
}

// Phase 3: read packed (xc,de), seeded scan, emit y (bf16).
__global__ __launch_bounds__(256) void scan_p3(
    const unsigned int* __restrict__ xde,
    const float* __restrict__ xdf, const float* __restrict__ xdb,
    const float* __restrict__ Alogf, const float* __restrict__ Alogb,
    const float* __restrict__ Dfp, const float* __restrict__ Dbp,
    const float* Hin,
    unsigned short* __restrict__ yf, unsigned short* __restrict__ yb)
{
  int chunk = blockIdx.x, b = blockIdx.y, dir = blockIdx.z;
  const float* xd   = dir ? xdb : xdf;
  const float* Alog = dir ? Alogb : Alogf;
  int d = threadIdx.x;

  __shared__ float sBC[CLEN*16];   // 2 KB: B (0..7) and C (8..15) per step
  {
    const float* xdp = xd + ((size_t)b*LL + (size_t)chunk*CLEN)*32;
    #pragma unroll
    for (int e = threadIdx.x; e < CLEN*16; e += 256){
      int row = e >> 4, col = e & 15;
      sBC[e] = xdp[row*32 + 16 + col];
    }
  }
  __syncthreads();

  float A[NST];
  #pragma unroll
  for (int n = 0; n < NST; n++) A[n] = -__expf(Alog[d*NST + n]);
  float Dd = (dir ? Dbp : Dfp)[d];

  float h[NST];
  {
    size_t ib = ((((size_t)dir*CH + chunk)*BB + b)*DD + d)*NST;
    float4 a0 = *(const float4*)&Hin[ib];
    float4 a1 = *(const float4*)&Hin[ib+4];
    h[0]=a0.x; h[1]=a0.y; h[2]=a0.z; h[3]=a0.w;
    h[4]=a1.x; h[5]=a1.y; h[6]=a1.z; h[7]=a1.w;
  }

  int base = chunk*CLEN;
  const unsigned int* xdep = xde + ((size_t)(dir*BB + b)*LL + base)*DD + d;
  unsigned short* yp = (dir ? yb : yf) + ((size_t)b*LL + base)*DD + d;

  const int U = 8;
  unsigned int pk[U];
  #pragma unroll
  for (int u = 0; u < U; u++) pk[u] = xdep[(size_t)u*DD];

  for (int t0 = 0; t0 < CLEN; t0 += U){
    unsigned int nk[U];
    if (t0 + U < CLEN){
      #pragma unroll
      for (int u = 0; u < U; u++) nk[u] = xdep[(size_t)(t0+U+u)*DD];
    }
    #pragma unroll
    for (int u = 0; u < U; u++){
      int t = t0 + u;
      float xc = bf2f((unsigned short)(pk[u] & 0xffffu));
      float de = bf2f((unsigned short)(pk[u] >> 16));
      float dux = de * xc;
      const float4 Bv0 = *(const float4*)&sBC[t*16 + 0];
      const float4 Bv1 = *(const float4*)&sBC[t*16 + 4];
      const float4 Cv0 = *(const float4*)&sBC[t*16 + 8];
      const float4 Cv1 = *(const float4*)&sBC[t*16 + 12];
      float acc = xc * Dd;
      h[0] = fmaf(__expf(de*A[0]), h[0], dux*Bv0.x); acc = fmaf(h[0], Cv0.x, acc);
      h[1] = fmaf(__expf(de*A[1]), h[1], dux*Bv0.y); acc = fmaf(h[1], Cv0.y, acc);
      h[2] = fmaf(__expf(de*A[2]), h[2], dux*Bv0.z); acc = fmaf(h[2], Cv0.z, acc);
      h[3] = fmaf(__expf(de*A[3]), h[3], dux*Bv0.w); acc = fmaf(h[3], Cv0.w, acc);
      h[4] = fmaf(__expf(de*A[4]), h[4], dux*Bv1.x); acc = fmaf(h[4], Cv1.x, acc);
      h[5] = fmaf(__expf(de*A[5]), h[5], dux*Bv1.y); acc = fmaf(h[5], Cv1.y, acc);
      h[6] = fmaf(__expf(de*A[6]), h[6], dux*Bv1.z); acc = fmaf(h[6], Cv1.z, acc);
      h[7] = fmaf(__expf(de*A[7]), h[7], dux*Bv1.w); acc = fmaf(h[7], Cv1.w, acc);
      yp[(size_t)t*DD] = f2bf(acc);
    }
    if (t0 + U < CLEN){
      #pragma unroll
      for (int u = 0; u < U; u++) pk[u] = nk[u];
    }
  }
}

// ---------------- Combine: y=(yf+flip(yb))/2 -> rmsnorm -> *silu(z) -> bf16 ------
__global__ __launch_bounds__(64) void combine_kernel(
    const unsigned short* __restrict__ yf, const unsigned short* __restrict__ yb,
    const unsigned short* __restrict__ zb, const float* __restrict__ wn,
    unsigned short* __restrict__ outb)
{
  size_t tok = blockIdx.x;
  int b = (int)(tok / LL), t = (int)(tok % LL);
  int lane = threadIdx.x;
  ushort4 au = ((const ushort4*)(yf + tok*DD))[lane];
  ushort4 cu = ((const ushort4*)(yb + ((size_t)b*LL + (LL-1-t))*DD))[lane];
  float4 v;
  v.x=(bf2f(au.x)+bf2f(cu.x))*0.5f; v.y=(bf2f(au.y)+bf2f(cu.y))*0.5f;
  v.z=(bf2f(au.z)+bf2f(cu.z))*0.5f; v.w=(bf2f(au.w)+bf2f(cu.w))*0.5f;
  float s = v.x*v.x + v.y*v.y + v.z*v.z + v.w*v.w;
  #pragma unroll
  for (int m = 1; m < 64; m <<= 1) s += __shfl_xor(s, m, 64);
  float scale = 1.f / (sqrtf(s)*(1.f/16.f) + 1e-6f);
  float4 wv = ((const float4*)wn)[lane];
  ushort4 zv = ((const ushort4*)(zb + tok*DD))[lane];
  ushort4 r;
  r.x = f2bf(v.x*scale*wv.x*siluf(bf2f(zv.x)));
  r.y = f2bf(v.y*scale*wv.y*siluf(bf2f(zv.y)));
  r.z = f2bf(v.z*scale*wv.z*siluf(bf2f(zv.z)));
  r.w = f2bf(v.w*scale*wv.w*siluf(bf2f(zv.w)));
  ((ushort4*)(outb + tok*DD))[lane] = r;
}

// ---------------- FF depthwise conv k=3 pad(1,1) + SiLU -> bf16 ------------------
__global__ __launch_bounds__(256) void dwconv3_kernel(
    const float* __restrict__ m, const float* __restrict__ w,
    const float* __restrict__ bi, unsigned short* __restrict__ o)
{
  size_t gid = (size_t)blockIdx.x*256 + threadIdx.x;  // over BL*HID
  int c = (int)(gid % HID);
  int tok = (int)(gid / HID);
  int b = tok / LL, t = tok % LL;
  float acc = bi[c];
  #pragma unroll
  for (int k = 0; k < 3; k++){
    int tt = t - 1 + k;
    if (tt >= 0 && tt < LL)
      acc = fmaf(w[c*3 + k], m[((size_t)b*LL + tt)*HID + c], acc);
  }
  o[gid] = f2bf(siluf(acc));
}

extern "C" void kernel_launch(void* const* d_in, const int* in_sizes, int n_in,
                              void* d_out, int out_size, void* d_ws, size_t ws_size,
                              hipStream_t stream)
{
  const float* x0        = (const float*)d_in[0];
  const float* x1        = (const float*)d_in[1];
  const float* w_norm0   = (const float*)d_in[2];
  const float* w_norm1   = (const float*)d_in[3];
  const float* in_proj_w = (const float*)d_in[4];
  const float* conv_w_f  = (const float*)d_in[5];
  const float* conv_b_f  = (const float*)d_in[6];
  const float* xproj_w_f = (const float*)d_in[7];
  const float* dtproj_w_f= (const float*)d_in[8];
  const float* dtproj_b_f= (const float*)d_in[9];
  const float* A_log_f   = (const float*)d_in[10];
  const float* D_f       = (const float*)d_in[11];
  const float* conv_w_bw = (const float*)d_in[12];
  const float* conv_b_bw = (const float*)d_in[13];
  const float* xproj_w_bw= (const float*)d_in[14];
  const float* dtproj_w_bw=(const float*)d_in[15];
  const float* dtproj_b_bw=(const float*)d_in[16];
  const float* A_log_bw  = (const float*)d_in[17];
  const float* D_bw      = (const float*)d_in[18];
  const float* norm_y_w  = (const float*)d_in[19];
  const float* out_proj_w= (const float*)d_in[20];
  const float* fc1_w     = (const float*)d_in[21];
  const float* dw_w      = (const float*)d_in[22];
  const float* dw_b      = (const float*)d_in[23];
  const float* fc2_w     = (const float*)d_in[24];
  float* out = (float*)d_out;
  float* ws  = (float*)d_ws;

  // region map (floats), lifetime-reused
  float* r0 = ws + 0*BLD;   // h0b (bf16) -> yfb (bf16)
  float* r1 = ws + 1*BLD;   // h1 (fp32)  -> ybb (bf16)
  float* r2 = ws + 2*BLD;   // xin_b (bf16, live until p1) -> ycomb_b (bf16)
  float* r3 = ws + 3*BLD;   // zb (bf16, live until combine)
  float* r4 = ws + 4*BLD;   // xde (uint32, spans r4+r5) -> m1 (fp32)
  float* r5 = ws + 5*BLD;   //                           -> m2b (bf16)
  float* r6 = ws + 6*BLD;   // wbuf1 (bf16) -> P/Hout carries (Hin aliases P)
  float* r7 = ws + 7*BLD;   // wbuf2 (bf16 weights) + xb (bf16)
  float* xdf  = ws + 8*BLD;            // BL*32
  float* xdb  = ws + 8*BLD + (size_t)BL*32;

  unsigned short* h0b   = (unsigned short*)r0;
  float*          h1    = r1;
  unsigned short* xin_b = (unsigned short*)r2;
  unsigned short* zb    = (unsigned short*)r3;
  unsigned int*   xde   = (unsigned int*)r4;     // 2*BLD dwords = r4+r5
  unsigned short* wbuf1 = (unsigned short*)r6;   // 131072
  unsigned short* yfb   = (unsigned short*)r0;
  unsigned short* ybb   = (unsigned short*)r1;
  const size_t CARRY = (size_t)2*CH*BB*DD*NST;   // 2,097,152 floats (8 MB)
  float* Pbuf = r6;
  float* Hout = r6 + CARRY;
  float* Hin  = Pbuf;                            // aliased; p2 reads-then-writes
  unsigned short* ycomb_b = (unsigned short*)r2;
  unsigned short* wbuf2   = (unsigned short*)r7;
  unsigned short* wb_out  = wbuf2;            // 65536
  unsigned short* wb_fc1  = wbuf2 + 65536;    // 32768
  unsigned short* wb_fc2  = wbuf2 + 98304;    // 32768
  unsigned short* xb      = wbuf2 + 131072;   // BLD bf16
  float*          m1      = r4;
  unsigned short* m2b     = (unsigned short*)r5;

  // 0. weight conversions
  cvt1_kernel<<<dim3(512), 256, 0, stream>>>(in_proj_w, wbuf1, 131072);
  cvt3_kernel<<<dim3(512), 256, 0, stream>>>(out_proj_w, fc1_w, fc2_w, wbuf2);

  // 1. RMSNorm x0 -> h0b (bf16), x1 -> h1 (fp32)
  rms_kernel<<<dim3(BL,2), 64, 0, stream>>>(x0, w_norm0, h0b, x1, w_norm1, h1);

  // 2. xz = h0 @ in_proj_w.T -> xin_b (bf16), zb (bf16)
  gemm_mfma<3><<<dim3(BL/64, 4), 256, 0, stream>>>(
      h0b, wbuf1, nullptr, nullptr, xin_b, BL, 256, 256);
  gemm_mfma<3><<<dim3(BL/64, 4), 256, 0, stream>>>(
      h0b, wbuf1 + 65536, nullptr, nullptr, zb, BL, 256, 256);

  // 3. x_dbl = ctx @ xproj.T (fp32; forward h1, backward flipped h1)
  gemm_abt<64,32,16,4,2><<<dim3(BL/64,1), 256, 0, stream>>>(
      h1, xproj_w_f, xdf, BL, 32, 256, 256, 0);
  gemm_abt<64,32,16,4,2><<<dim3(BL/64,1), 256, 0, stream>>>(
      h1, xproj_w_bw, xdb, BL, 32, 256, 256, 1);

  // 4-6. chunk-parallel scan: p1 (conv+delta inline, packs xc/de), carry, p3
  scan_p1<<<dim3(CH,BB,2), 256, 0, stream>>>(
      xin_b, xdf, xdb, conv_w_f, conv_b_f, conv_w_bw, conv_b_bw,
      dtproj_w_f, dtproj_b_f, dtproj_w_bw, dtproj_b_bw,
      A_log_f, A_log_bw, xde, Pbuf, Hout);
  scan_p2<<<dim3(64), 256, 0, stream>>>(Pbuf, Hout, Hin);
  scan_p3<<<dim3(CH,BB,2), 256, 0, stream>>>(
      xde, xdf, xdb, A_log_f, A_log_bw, D_f, D_bw, Hin, yfb, ybb);

  // 7. combine + rmsnorm + gate -> bf16 (r2; xin dead)
  combine_kernel<<<dim3(BL), 64, 0, stream>>>(yfb, ybb, zb, norm_y_w, ycomb_b);

  // 8. x = y @ out_proj.T + residual(x0) -> d_out (fp32) + xb (bf16)
  gemm_mfma<1><<<dim3(BL/64, 4), 256, 0, stream>>>(
      ycomb_b, wb_out, out, x0, xb, BL, 256, 256);

  // 9. m1 = x @ fc1.T (fp32; overwrites dead xde)
  gemm_mfma<0><<<dim3(BL/64, 2), 256, 0, stream>>>(
      xb, wb_fc1, m1, nullptr, nullptr, BL, 128, 256);

  // 10. m2 = silu(dwconv3(m1)) -> bf16
  dwconv3_kernel<<<dim3((BL*HID)/256), 256, 0, stream>>>(m1, dw_w, dw_b, m2b);

  // 11. out = x + m2 @ fc2.T
  gemm_mfma<2><<<dim3(BL/64, 4), 256, 0, stream>>>(
      m2b, wb_fc2, out, out, nullptr, BL, 256, 128);
}